// Round 2
// baseline (360.167 us; speedup 1.0000x reference)
//
#include <hip/hip_runtime.h>

// Contracter: out[z,u,k] = sum_{i,j} x1[z,u,i]*x2[z,u,j]*ww[u,k,i,j],
// ww[u,k,i,j] = sum_p weights[u,p]*w3j[p,k,i,j]. Z=50000, 64 channels, BASE=9.
//
// R1 post-mortem: strided per-lane access (36B @ 2304B stride) made every
// load/store instruction scatter to 64 cache lines -> 1728 L1 transactions
// per wave -> 140us TCP-bound (measured 144us, HBM 20%, VALU 34%).
//
// R2: LDS staging decouples coalescing from compute assignment.
//  - block 256 = 4 waves; tile = 64 z x 16 u, in 4 chunks of 4 u.
//  - stage-in: coalesced float4 global loads -> ds_write_b64 into padded tile.
//  - compute: wave-uniform u (ww row via SMRD), per-path sparse-block
//    contraction (363 FMA + 115 mul instead of dense 729+81).
//  - stage-out: LDS out-tile -> coalesced float4 stores.
//  - XCD swizzle: the 4 u-range blocks of one z-tile land on one XCD so its
//    L2 assembles full lines from the 144B-per-z chunks.

#define MUL    64
#define BASE   9
#define NPATH  11
#define ZT     64    // z per tile (one per lane)
#define UC     4     // u per chunk (one per wave)
#define NCH    4     // chunks per block -> 16 u per block
#define URANGE (UC*NCH)
#define PAD    38    // LDS floats per z-row (36 used; 38 => 8B-align + mild conflicts)

__global__ __launch_bounds__(256) void fold_kernel(
    const float* __restrict__ weights,   // (64, 11)
    const float* __restrict__ w3j,       // (11, 729)
    float*       __restrict__ ww)        // (64, 729) out
{
    int u = blockIdx.x / 3;
    int t = (blockIdx.x % 3) * 256 + threadIdx.x;
    if (t >= 729) return;
    float acc = 0.f;
#pragma unroll
    for (int p = 0; p < NPATH; ++p)
        acc = fmaf(weights[u * NPATH + p], w3j[p * 729 + t], acc);
    ww[u * 729 + t] = acc;
}

__device__ __forceinline__ void stage_in(
    const float* __restrict__ x1, const float* __restrict__ x2,
    float* s1, float* s2, int z0, int ucbase, int Z, int t)
{
    // chunk = 64 z x 36 floats (4u x 9i), contiguous 144B per z in global.
    // 576 float4 per buffer; thread t handles e = t, t+256, t+512(partial).
    for (int e = t; e < ZT * 9; e += 256) {
        int z  = e / 9;
        int c4 = (e - z * 9) * 4;               // float offset within 36
        if (z0 + z < Z) {
            int g = (z0 + z) * (MUL * BASE) + ucbase * BASE + c4;
            float4 v1 = *(const float4*)(x1 + g);
            float4 v2 = *(const float4*)(x2 + g);
            int a = z * PAD + c4;
            *(float2*)(s1 + a)     = make_float2(v1.x, v1.y);
            *(float2*)(s1 + a + 2) = make_float2(v1.z, v1.w);
            *(float2*)(s2 + a)     = make_float2(v2.x, v2.y);
            *(float2*)(s2 + a + 2) = make_float2(v2.z, v2.w);
        }
    }
}

__device__ __forceinline__ void stage_out(
    float* __restrict__ out, const float* so, int z0, int ucbase, int Z, int t)
{
    for (int e = t; e < ZT * 9; e += 256) {
        int z  = e / 9;
        int c4 = (e - z * 9) * 4;
        if (z0 + z < Z) {
            int a = z * PAD + c4;
            float2 lo = *(const float2*)(so + a);
            float2 hi = *(const float2*)(so + a + 2);
            int g = (z0 + z) * (MUL * BASE) + ucbase * BASE + c4;
            *(float4*)(out + g) = make_float4(lo.x, lo.y, hi.x, hi.y);
        }
    }
}

__global__ __launch_bounds__(256) void tp_kernel(
    const float* __restrict__ x1,
    const float* __restrict__ x2,
    const float* __restrict__ ww,        // (64, 729)
    float*       __restrict__ out,
    int Z, int n_zt)
{
    __shared__ float s1[ZT * PAD];
    __shared__ float s2[ZT * PAD];
    __shared__ float so[ZT * PAD];

    // XCD swizzle: all 4 u-range blocks of one z-tile on the same XCD.
    int g    = blockIdx.x;
    int xcd  = g & 7;
    int loc  = g >> 3;
    int ur   = loc & 3;
    int zt   = (loc >> 2) * 8 + xcd;
    if (zt >= n_zt) return;

    int t    = threadIdx.x;
    int wave = t >> 6;
    int lane = t & 63;
    int z0   = zt * ZT;
    int u0   = ur * URANGE;

    // path table: (i1, i2, io) indices into L/OFF
    constexpr int P1[NPATH] = {0,0,0,1,1,1,1,2,2,2,2};
    constexpr int P2[NPATH] = {0,1,2,0,1,1,2,0,1,2,2};
    constexpr int PO[NPATH] = {0,1,2,1,0,2,1,2,1,0,2};
    constexpr int NL[3]  = {1,3,5};
    constexpr int OFF[3] = {0,1,4};

#pragma unroll 1
    for (int c = 0; c < NCH; ++c) {
        __syncthreads();   // prev compute done with s1/s2; prev stage_out done with so
        stage_in(x1, x2, s1, s2, z0, u0 + c * UC, Z, t);
        if (c > 0) stage_out(out, so, z0, u0 + (c - 1) * UC, Z, t);
        __syncthreads();   // staging visible; so free for this chunk's compute

        int u = u0 + c * UC + wave;
        u = __builtin_amdgcn_readfirstlane(u);          // wave-uniform -> SMRD
        const float* __restrict__ wrow = ww + u * 729;

        float X1[BASE], X2[BASE];
        int base = lane * PAD + wave * BASE;
#pragma unroll
        for (int i = 0; i < BASE; ++i) {
            X1[i] = s1[base + i];
            X2[i] = s2[base + i];
        }

        float o[BASE];
#pragma unroll
        for (int k = 0; k < BASE; ++k) o[k] = 0.f;

#pragma unroll
        for (int p = 0; p < NPATH; ++p) {
            const int o1 = OFF[P1[p]], n1 = NL[P1[p]];
            const int o2 = OFF[P2[p]], n2 = NL[P2[p]];
            const int oo = OFF[PO[p]], no = NL[PO[p]];
#pragma unroll
            for (int i = 0; i < n1; ++i) {
                float a = X1[o1 + i];
#pragma unroll
                for (int j = 0; j < n2; ++j) {
                    float rv = a * X2[o2 + j];
#pragma unroll
                    for (int k = 0; k < no; ++k)
                        o[oo + k] = fmaf(wrow[(oo + k) * 81 + (o1 + i) * 9 + (o2 + j)],
                                         rv, o[oo + k]);
                }
            }
        }

#pragma unroll
        for (int k = 0; k < BASE; ++k)
            so[base + k] = o[k];
    }
    __syncthreads();
    stage_out(out, so, z0, u0 + (NCH - 1) * UC, Z, t);
}

extern "C" void kernel_launch(void* const* d_in, const int* in_sizes, int n_in,
                              void* d_out, int out_size, void* d_ws, size_t ws_size,
                              hipStream_t stream) {
    const float* x1  = (const float*)d_in[0];
    const float* x2  = (const float*)d_in[1];
    const float* w   = (const float*)d_in[2];   // (64, 11)
    const float* w3j = (const float*)d_in[3];   // (11, 729)
    float* out = (float*)d_out;
    float* ww  = (float*)d_ws;                  // (64, 729) scratch

    int Z = in_sizes[0] / (MUL * BASE);

    fold_kernel<<<MUL * 3, 256, 0, stream>>>(w, w3j, ww);

    int n_zt = (Z + ZT - 1) / ZT;              // 782
    int q    = (n_zt + 7) / 8;                 // z-tiles per XCD lane
    int grid = 8 * 4 * q;                      // xcd x u-range x q
    tp_kernel<<<grid, 256, 0, stream>>>(x1, x2, ww, out, Z, n_zt);
}